// Round 1
// baseline (41.708 us; speedup 1.0000x reference)
//
#include <hip/hip_runtime.h>
#include <hip/hip_bf16.h>

typedef __attribute__((ext_vector_type(4))) float  f32x4;
typedef __attribute__((ext_vector_type(8))) short  s16x8;
typedef __attribute__((ext_vector_type(4))) short  s16x4;

static __device__ __forceinline__ short f2bf(float x) {
    union { float f; unsigned u; } un; un.f = x;
    unsigned r = un.u + 0x7fffu + ((un.u >> 16) & 1u);   // RNE to bf16
    return (short)(r >> 16);
}

// load 8 consecutive f32 at [row*stride + k0], convert to bf16 fragment
static __device__ __forceinline__ s16x8 load_frag_f32(const float* __restrict__ base,
                                                      int stride, int row, int k0) {
    const float* p = base + (size_t)row * stride + k0;
    f32x4 a = *(const f32x4*)p;
    f32x4 b = *(const f32x4*)(p + 4);
    s16x8 f;
    f[0]=f2bf(a[0]); f[1]=f2bf(a[1]); f[2]=f2bf(a[2]); f[3]=f2bf(a[3]);
    f[4]=f2bf(b[0]); f[5]=f2bf(b[1]); f[6]=f2bf(b[2]); f[7]=f2bf(b[3]);
    return f;
}

#define MFMA(a,b,c) __builtin_amdgcn_mfma_f32_16x16x32_bf16((a),(b),(c),0,0,0)

__global__ __launch_bounds__(256, 2) void dlsa_kernel(
    const float* __restrict__ h_pos, const float* __restrict__ h_geo,
    const float* __restrict__ Wq, const float* __restrict__ bq,
    const float* __restrict__ Wk, const float* __restrict__ bk,
    const float* __restrict__ Wv, const float* __restrict__ bv,
    const float* __restrict__ Wo, const float* __restrict__ bo,
    float* __restrict__ out)
{
    constexpr int D = 32, S = 128, NN = 16384;
    constexpr int QS = 40;    // stride (shorts) for 128x32 bf16 tiles (80 B rows)
    constexpr int PS = 136;   // stride (shorts) for 128-wide bf16 tiles (272 B rows)

    __shared__ __align__(16) short sQ[128 * QS];   // Q rows; reused for O
    __shared__ __align__(16) short sK[128 * QS];
    __shared__ __align__(16) short sVt[32 * PS];   // V transposed: Vt[d][t]
    __shared__ __align__(16) short sP[128 * PS];

    const int tid = threadIdx.x;
    const int wv  = tid >> 6;
    const int ln  = tid & 63;
    const int lr  = ln & 15;          // row/col within 16-tile
    const int lg  = ln >> 4;          // k-group 0..3
    const int lk  = lg << 3;          // k offset 0,8,16,24

    const int blk = blockIdx.x;
    const int b   = blk >> 7;         // batch
    const int c   = blk & 127;        // cluster
    const float* xg = h_geo + (size_t)(b * NN + c * S) * D;
    const float* xp = h_pos + (size_t)(b * NN + c * S) * D;

    // ---- weight B-fragments + biases in registers (B[k][n] = W[n][k] -> read W rows) ----
    s16x8 fWq[2], fWk[2], fWv[2], fWo[2];
    float vbq[2], vbk[2], vbv[2], vbo[2];
#pragma unroll
    for (int ni = 0; ni < 2; ++ni) {
        int n = ni * 16 + lr;
        fWq[ni] = load_frag_f32(Wq, 32, n, lk);
        fWk[ni] = load_frag_f32(Wk, 32, n, lk);
        fWv[ni] = load_frag_f32(Wv, 32, n, lk);
        fWo[ni] = load_frag_f32(Wo, 32, n, lk);
        vbq[ni] = bq[n]; vbk[ni] = bk[n]; vbv[ni] = bv[n]; vbo[ni] = bo[n];
    }

    // ---- X A-fragments for this wave's 32 rows ----
    const int r0 = wv * 32;
    s16x8 aXg[2], aXp[2];
#pragma unroll
    for (int mi = 0; mi < 2; ++mi) {
        aXg[mi] = load_frag_f32(xg, D, r0 + mi * 16 + lr, lk);
        aXp[mi] = load_frag_f32(xp, D, r0 + mi * 16 + lr, lk);
    }

    const f32x4 z4 = {0.f, 0.f, 0.f, 0.f};
    constexpr float inv_sqrt_d = 0.17677669529663687f;   // 1/sqrt(32)

    // ---- projections: Q,K -> LDS rows ; V -> LDS transposed ----
#pragma unroll
    for (int mi = 0; mi < 2; ++mi) {
#pragma unroll
        for (int ni = 0; ni < 2; ++ni) {
            f32x4 q = MFMA(aXg[mi], fWq[ni], z4);
            f32x4 k = MFMA(aXg[mi], fWk[ni], z4);
            f32x4 v = MFMA(aXp[mi], fWv[ni], z4);
            int row = r0 + mi * 16 + lg * 4;   // + r
            int col = ni * 16 + lr;
#pragma unroll
            for (int r = 0; r < 4; ++r) {
                sQ[(row + r) * QS + col] = f2bf((q[r] + vbq[ni]) * inv_sqrt_d);
                sK[(row + r) * QS + col] = f2bf(k[r] + vbk[ni]);
            }
            s16x4 vp;
#pragma unroll
            for (int r = 0; r < 4; ++r) vp[r] = f2bf(v[r] + vbv[ni]);
            *(s16x4*)&sVt[col * PS + row] = vp;   // Vt[col][row..row+3]
        }
    }
    __syncthreads();

    // ---- scores = Qc Kc^T for this wave's 32 rows; accumulators stay in regs ----
    s16x8 aQ0 = *(const s16x8*)&sQ[(r0 + lr) * QS + lk];
    s16x8 aQ1 = *(const s16x8*)&sQ[(r0 + 16 + lr) * QS + lk];
    f32x4 sc[2][8];
#pragma unroll
    for (int nt = 0; nt < 8; ++nt) {
        s16x8 kb = *(const s16x8*)&sK[(nt * 16 + lr) * QS + lk];
        sc[0][nt] = MFMA(aQ0, kb, z4);
        sc[1][nt] = MFMA(aQ1, kb, z4);
    }

    // ---- in-register row softmax ; P -> LDS bf16 ----
#pragma unroll
    for (int mi = 0; mi < 2; ++mi) {
#pragma unroll
        for (int r = 0; r < 4; ++r) {
            float m = sc[mi][0][r];
#pragma unroll
            for (int nt = 1; nt < 8; ++nt) m = fmaxf(m, sc[mi][nt][r]);
            m = fmaxf(m, __shfl_xor(m, 1));
            m = fmaxf(m, __shfl_xor(m, 2));
            m = fmaxf(m, __shfl_xor(m, 4));
            m = fmaxf(m, __shfl_xor(m, 8));
            float p[8]; float s = 0.f;
#pragma unroll
            for (int nt = 0; nt < 8; ++nt) { p[nt] = __expf(sc[mi][nt][r] - m); s += p[nt]; }
            s += __shfl_xor(s, 1);
            s += __shfl_xor(s, 2);
            s += __shfl_xor(s, 4);
            s += __shfl_xor(s, 8);
            float inv = __builtin_amdgcn_rcpf(s);
            int row = r0 + mi * 16 + lg * 4 + r;
#pragma unroll
            for (int nt = 0; nt < 8; ++nt)
                sP[row * PS + nt * 16 + lr] = f2bf(p[nt] * inv);
        }
    }
    __syncthreads();

    // ---- O = P V (rows r0..r0+31, all 32 cols) ----
    f32x4 accO[2][2] = {{z4, z4}, {z4, z4}};
#pragma unroll
    for (int kt = 0; kt < 4; ++kt) {
        s16x8 pa0 = *(const s16x8*)&sP[(r0 + lr) * PS + kt * 32 + lk];
        s16x8 pa1 = *(const s16x8*)&sP[(r0 + 16 + lr) * PS + kt * 32 + lk];
        s16x8 vb0 = *(const s16x8*)&sVt[(lr) * PS + kt * 32 + lk];
        s16x8 vb1 = *(const s16x8*)&sVt[(16 + lr) * PS + kt * 32 + lk];
        accO[0][0] = MFMA(pa0, vb0, accO[0][0]);
        accO[0][1] = MFMA(pa0, vb1, accO[0][1]);
        accO[1][0] = MFMA(pa1, vb0, accO[1][0]);
        accO[1][1] = MFMA(pa1, vb1, accO[1][1]);
    }

    // ---- O -> LDS bf16 (reuse sQ; only this wave's rows touched) ----
#pragma unroll
    for (int mi = 0; mi < 2; ++mi) {
#pragma unroll
        for (int ni = 0; ni < 2; ++ni) {
            int row = r0 + mi * 16 + lg * 4;
            int col = ni * 16 + lr;
#pragma unroll
            for (int r = 0; r < 4; ++r)
                sQ[(row + r) * QS + col] = f2bf(accO[mi][ni][r]);
        }
    }
    __syncthreads();

    // ---- Y = O Wo^T + bo -> global ----
    s16x8 aO0 = *(const s16x8*)&sQ[(r0 + lr) * QS + lk];
    s16x8 aO1 = *(const s16x8*)&sQ[(r0 + 16 + lr) * QS + lk];
    float* outp = out + (size_t)(b * NN + c * S) * D;
#pragma unroll
    for (int mi = 0; mi < 2; ++mi) {
        s16x8 aO = mi ? aO1 : aO0;
#pragma unroll
        for (int ni = 0; ni < 2; ++ni) {
            f32x4 y = MFMA(aO, fWo[ni], z4);
            int row = r0 + mi * 16 + lg * 4;
            int col = ni * 16 + lr;
#pragma unroll
            for (int r = 0; r < 4; ++r)
                outp[(size_t)(row + r) * D + col] = y[r] + vbo[ni];
        }
    }
}

extern "C" void kernel_launch(void* const* d_in, const int* in_sizes, int n_in,
                              void* d_out, int out_size, void* d_ws, size_t ws_size,
                              hipStream_t stream) {
    const float* h_pos = (const float*)d_in[0];
    const float* h_geo = (const float*)d_in[1];
    // d_in[2] = n_clusters (128) — geometry hardcoded
    const float* Wq = (const float*)d_in[3];
    const float* bq = (const float*)d_in[4];
    const float* Wk = (const float*)d_in[5];
    const float* bk = (const float*)d_in[6];
    const float* Wv = (const float*)d_in[7];
    const float* bv = (const float*)d_in[8];
    const float* Wo = (const float*)d_in[9];
    const float* bo = (const float*)d_in[10];
    dlsa_kernel<<<dim3(2048), dim3(256), 0, stream>>>(
        h_pos, h_geo, Wq, bq, Wk, bk, Wv, bv, Wo, bo, (float*)d_out);
}